// Round 5
// baseline (103.203 us; speedup 1.0000x reference)
//

#include <hip/hip_runtime.h>

// RadiusInteractionGraph: B=128 molecules x 512 atoms, K=32 NN, cutoff 10.
// d_out is FLOAT32: [E] src ++ [E] dst ++ [E] weight, E = 128*512*32.
//
// R26 = R24/R25 base (pk-f32 build, all-VALU exchanges, dual-half epilogue)
// with two EXACT straight-line op cuts. Ledger R21-R25: wall pinned 48-50us,
// VALU issue 36-38us -> VALU-issue-bound; only op-count cuts move it; R25
// showed branchy early-exit de-pipelines (stall grew). So: branchless cuts.
//  (1) EXPONENT-LADDER rank search, 11 -> 6 count-rounds. The greedy walk's
//      X = max{2^21-grid pt : count(<X)<32}. Binary-search (3 rounds) the 7
//      exponent thresholds L[i]=(0x7E+i)<<23 (d2=0.5..32) for largest i with
//      count<32; for every reachable outcome the upper neighbor was tested-
//      and-rejected, so X* in [L[i],L[i+1]) => bits 30..23 of X* == exponent
//      of L[i] exactly. Then 2 greedy rounds (bits 22,21) == original walk.
//      Outcomes i*<0 (32 NN within d2<0.5) or i*>=6 (32nd key at d2>=32 or
//      sentinel region): wave-uniform branch to the ORIGINAL full 10-round
//      walk -> unconditionally exact. Verify + W>64 refine unchanged.
//  (2) SHARED SORT TAIL, 2x21+swap -> 2x16+1+5 steps. Ranks 32-63 are
//      discarded, so: head stages K=2..32 + one <64,32> half-cleaner per row
//      (A,B interleaved), then pack A-low into lanes 0-31 / B-low into lanes
//      32-63 (the permlane32 that WAS the epilogue swap) and run the final
//      5 merge steps (strides 16..1 never cross the 32-boundary; keepmin=
//      (lane&J)==0 is the ascending merge both halves need) ONCE.
// Selection semantics bit-identical: key=(d2_hi23|j) lex == lax.top_k stable
// order; exact __f*_rn np arithmetic (pk-f32 is IEEE-exact per half, and
// s-2*dot == s+(-2)*dot under RN); sentinel 0x7F800000|j -> pad self-edge.

constexpr int EDGES = 128 * 512 * 32;   // 2097152

typedef float f32x2 __attribute__((ext_vector_type(2)));

static __device__ __forceinline__ f32x2 pk_mul(f32x2 a, f32x2 b) {
    f32x2 d;
    asm("v_pk_mul_f32 %0, %1, %2" : "=v"(d) : "v"(a), "v"(b));
    return d;
}
static __device__ __forceinline__ f32x2 pk_add(f32x2 a, f32x2 b) {
    f32x2 d;
    asm("v_pk_add_f32 %0, %1, %2" : "=v"(d) : "v"(a), "v"(b));
    return d;
}

static __device__ __forceinline__ unsigned umin2(unsigned a, unsigned b) {
    return a < b ? a : b;
}
static __device__ __forceinline__ unsigned umax2(unsigned a, unsigned b) {
    return a > b ? a : b;
}

static __device__ __forceinline__ unsigned mbcnt64(unsigned long long m) {
    return __builtin_amdgcn_mbcnt_hi(
        (unsigned)(m >> 32),
        __builtin_amdgcn_mbcnt_lo((unsigned)m, 0u));
}

static __device__ __forceinline__ unsigned count_lt(const unsigned q[8],
                                                    unsigned C) {
    unsigned cnt = 0;
#pragma unroll
    for (int c = 0; c < 8; ++c)
        cnt += (unsigned)__popcll(__ballot(q[c] < C));
    return cnt;
}

// original greedy MSB walk over bits 30..21 (exact; rare fallback path)
static __device__ __forceinline__ unsigned full_walk(const unsigned q[8]) {
    unsigned X = 0u;
    for (int bit = 30; bit >= 21; --bit) {
        const unsigned C = X | (1u << bit);
        if (count_lt(q, C) < 32u) X = C;
    }
    return X;
}

// xor-partner fetch, all-VALU (no LDS pipe). Patterns verified (R24 PASS):
//  quad_perm 0xB1 = ^1, 0x4E = ^2, 0x1B = ^3; 0x141 row_half_mirror = ^7
//  within 8; 0x128 row_ror:8 = ^8 within 16 (+8 mod 16 == ^8).
template <int J>
static __device__ __forceinline__ unsigned xpart(unsigned v, int lane) {
    if constexpr (J == 1) {
        return (unsigned)__builtin_amdgcn_update_dpp(
            (int)v, (int)v, 0xB1, 0xF, 0xF, false);
    } else if constexpr (J == 2) {
        return (unsigned)__builtin_amdgcn_update_dpp(
            (int)v, (int)v, 0x4E, 0xF, 0xF, false);
    } else if constexpr (J == 4) {
        const int t = __builtin_amdgcn_update_dpp(
            (int)v, (int)v, 0x141, 0xF, 0xF, false);   // ^7 within 8
        return (unsigned)__builtin_amdgcn_update_dpp(
            t, t, 0x1B, 0xF, 0xF, false);              // ^3 -> net ^4
    } else if constexpr (J == 8) {
        return (unsigned)__builtin_amdgcn_update_dpp(
            (int)v, (int)v, 0x128, 0xF, 0xF, false);   // row_ror:8 = ^8
    } else if constexpr (J == 16) {
#if __has_builtin(__builtin_amdgcn_permlane16_swap)
        auto r = __builtin_amdgcn_permlane16_swap((int)v, (int)v, false, false);
        return (unsigned)((lane & 16) ? r[0] : r[1]);
#else
        return (unsigned)__shfl_xor((int)v, 16, 64);
#endif
    } else {
#if __has_builtin(__builtin_amdgcn_permlane32_swap)
        auto r = __builtin_amdgcn_permlane32_swap((int)v, (int)v, false, false);
        return (unsigned)((lane & 32) ? r[0] : r[1]);
#else
        return (unsigned)__shfl_xor((int)v, 32, 64);
#endif
    }
}

template <int K, int J>
static __device__ __forceinline__ void bstep(unsigned& v, int lane) {
    const unsigned p = xpart<J>(v, lane);
    const bool keepmin = (((lane & J) == 0) == ((lane & K) == 0));
    const unsigned mn = umin2(v, p);
    const unsigned mx = umax2(v, p);
    v = keepmin ? mn : mx;
}

// one step applied to both rows (independent chains fill stall slots;
// keepmin computed once)
template <int K, int J>
static __device__ __forceinline__ void bstep2(unsigned& a, unsigned& b,
                                              int lane) {
    const unsigned pa = xpart<J>(a, lane);
    const unsigned pb = xpart<J>(b, lane);
    const bool keepmin = (((lane & J) == 0) == ((lane & K) == 0));
    a = keepmin ? umin2(a, pa) : umax2(a, pa);
    b = keepmin ? umin2(b, pb) : umax2(b, pb);
}

// bitonic stages K=2..32 (15 steps/row), rows interleaved
static __device__ __forceinline__ void bitonic_head2(unsigned& a, unsigned& b,
                                                     int lane) {
    bstep2<2, 1>(a, b, lane);
    bstep2<4, 2>(a, b, lane);   bstep2<4, 1>(a, b, lane);
    bstep2<8, 4>(a, b, lane);   bstep2<8, 2>(a, b, lane);
    bstep2<8, 1>(a, b, lane);
    bstep2<16, 8>(a, b, lane);  bstep2<16, 4>(a, b, lane);
    bstep2<16, 2>(a, b, lane);  bstep2<16, 1>(a, b, lane);
    bstep2<32, 16>(a, b, lane); bstep2<32, 8>(a, b, lane);
    bstep2<32, 4>(a, b, lane);  bstep2<32, 2>(a, b, lane);
    bstep2<32, 1>(a, b, lane);
}

__global__ __launch_bounds__(256)
void RadiusInteractionGraph_73246372266582_kernel(const float* __restrict__ pos,
                                                  float* __restrict__ out) {
    __shared__ float4 atoms[512];        // x, y, z, |p|^2
    __shared__ unsigned wbuf[4][2][64];  // per-wave, per-interleaved-row

    const int tid     = threadIdx.x;
    const int b       = blockIdx.x >> 5;          // 32 blocks per molecule
    const int rowbase = (blockIdx.x & 31) * 16;   // 16 rows per block
    const int base    = b * 512;

    for (int a = tid; a < 512; a += 256) {
        float x = pos[(base + a) * 3 + 0];
        float y = pos[(base + a) * 3 + 1];
        float z = pos[(base + a) * 3 + 2];
        // np: sum(p*p) = (x*x + y*y) + z*z, sequential f32, no fma
        float sq = __fadd_rn(__fadd_rn(__fmul_rn(x, x), __fmul_rn(y, y)),
                             __fmul_rn(z, z));
        atoms[a] = make_float4(x, y, z, sq);
    }
    __syncthreads();

    const int wave = tid >> 6;
    const int lane = tid & 63;

    const f32x2 NEG2 = {-2.0f, -2.0f};

    for (int rp = 0; rp < 2; ++rp) {
        const int iA = rowbase + wave * 4 + rp * 2;
        const int iB = iA + 1;
        const float4 cA = atoms[iA];
        const float4 cB = atoms[iB];
        const f32x2 CX = {cA.x, cB.x};
        const f32x2 CY = {cA.y, cB.y};
        const f32x2 CZ = {cA.z, cB.z};
        const f32x2 CW = {cA.w, cB.w};

        // ---- build 8 UNIQUE keys per lane, rows A,B packed in pk-f32 ----
        unsigned qA[8], qB[8];
#pragma unroll
        for (int c = 0; c < 8; ++c) {
            const int j = c * 64 + lane;
            const float4 pj = atoms[j];           // one ds_read_b128, shared
            const f32x2 px = {pj.x, pj.x};
            const f32x2 py = {pj.y, pj.y};
            const f32x2 pz = {pj.z, pj.z};
            const f32x2 pw = {pj.w, pj.w};
            // np einsum order: ((xi*xj + yi*yj) + zi*zj), exact per half
            const f32x2 txx = pk_mul(CX, px);
            const f32x2 tyy = pk_mul(CY, py);
            const f32x2 sxy = pk_add(txx, tyy);
            const f32x2 tzz = pk_mul(CZ, pz);
            const f32x2 dot = pk_add(sxy, tzz);
            // d2 = (ci.w + pj.w) - 2*dot == (ci.w + pj.w) + (-2)*dot exactly
            const f32x2 sw  = pk_add(CW, pw);
            const f32x2 m2  = pk_mul(dot, NEG2);
            const f32x2 d2p = pk_add(sw, m2);
            const float d2A = fmaxf(d2p.x, 0.0f);
            const float d2B = fmaxf(d2p.y, 0.0f);
            qA[c] = ((j != iA) && (d2A <= 100.0f))
                        ? ((__float_as_uint(d2A) & 0xFFFFFE00u) | (unsigned)j)
                        : (0x7F800000u | (unsigned)j);
            qB[c] = ((j != iB) && (d2B <= 100.0f))
                        ? ((__float_as_uint(d2B) & 0xFFFFFE00u) | (unsigned)j)
                        : (0x7F800000u | (unsigned)j);
        }

        // ---- exponent-ladder rank search (3 + 2 + 1 rounds, branchless) --
        // Binary search the 7 thresholds L[i]=(0x7E+i)<<23 (d2=0.5..32) for
        // the largest i with count(<L[i]) < 32. For all reachable outcomes
        // in [0,5], L[i+1] was tested-and-rejected, pinning bits 30..23 of
        // the walk's X exactly. i* outside [0,5] -> exact full-walk fallback.
        int loA = -1, hiiA = 7, loB = -1, hiiB = 7;
#pragma unroll
        for (int r = 0; r < 3; ++r) {
            const int mA = (loA + hiiA) >> 1;
            const int mB = (loB + hiiB) >> 1;
            const unsigned CA = (unsigned)((0x7E + mA) << 23);
            const unsigned CB = (unsigned)((0x7E + mB) << 23);
            unsigned ca = 0, cb = 0;
#pragma unroll
            for (int c = 0; c < 8; ++c) {
                ca += (unsigned)__popcll(__ballot(qA[c] < CA));
                cb += (unsigned)__popcll(__ballot(qB[c] < CB));
            }
            if (ca < 32u) loA = mA; else hiiA = mA;
            if (cb < 32u) loB = mB; else hiiB = mB;
        }
        const bool fbA = (loA < 0) || (loA >= 6);
        const bool fbB = (loB < 0) || (loB >= 6);
        unsigned XA = (unsigned)((0x7E + loA) << 23);  // bogus if fbA (fixed below)
        unsigned XB = (unsigned)((0x7E + loB) << 23);
        // mantissa bits 22, 21: greedy, identical to the original walk
#pragma unroll
        for (int bit = 22; bit >= 21; --bit) {
            const unsigned CA = XA | (1u << bit);
            const unsigned CB = XB | (1u << bit);
            unsigned ca = 0, cb = 0;
#pragma unroll
            for (int c = 0; c < 8; ++c) {
                ca += (unsigned)__popcll(__ballot(qA[c] < CA));
                cb += (unsigned)__popcll(__ballot(qB[c] < CB));
            }
            if (ca < 32u) XA = CA;
            if (cb < 32u) XB = CB;
        }
        if (fbA) XA = full_walk(qA);   // rare, wave-uniform scalar branch
        if (fbB) XB = full_walk(qB);

        unsigned hiA = XA + (1u << 21);
        unsigned hiB = XB + (1u << 21);
        const unsigned WA = count_lt(qA, hiA);
        const unsigned WB = count_lt(qB, hiB);
        if (WA > 64u) {   // pathological: refine exactly (R19 path)
            for (int bit = 20; bit >= 0; --bit) {
                const unsigned C = XA | (1u << bit);
                if (count_lt(qA, C) < 32u) XA = C;
            }
            hiA = XA + 1u;
        }
        if (WB > 64u) {
            for (int bit = 20; bit >= 0; --bit) {
                const unsigned C = XB | (1u << bit);
                if (count_lt(qB, C) < 32u) XB = C;
            }
            hiB = XB + 1u;
        }

        // ---- compact both windows (ballot+mbcnt), sentinel-pad to 64 ----
        wbuf[wave][0][lane] = 0xFFFFFFFFu;
        wbuf[wave][1][lane] = 0xFFFFFFFFu;
        unsigned tA = 0, tB = 0;
#pragma unroll
        for (int c = 0; c < 8; ++c) {
            const bool sA = (qA[c] < hiA);
            const bool sB = (qB[c] < hiB);
            const unsigned long long mA = __ballot(sA);
            const unsigned long long mB = __ballot(sB);
            const unsigned oA = tA + mbcnt64(mA);
            const unsigned oB = tB + mbcnt64(mB);
            if (sA) wbuf[wave][0][oA] = qA[c];
            if (sB) wbuf[wave][1][oB] = qB[c];
            tA += (unsigned)__popcll(mA);
            tB += (unsigned)__popcll(mB);
        }

        unsigned vA = wbuf[wave][0][lane];   // per-wave LDS is in-order
        unsigned vB = wbuf[wave][1][lane];

        // ---- sort: heads + half-cleaners per row, then ONE shared tail ----
        bitonic_head2(vA, vB, lane);         // K=2..32, both rows
        bstep2<64, 32>(vA, vB, lane);        // half-cleaner: 32 smallest low
        // pack: A-low stays lanes 0-31; B-low -> lanes 32-63 (this permlane
        // replaces the old epilogue swap)
        unsigned z = (lane & 32) ? xpart<32>(vB, lane) : vA;
        // final ascending merge of each bitonic 32-half; strides never cross
        // the 32-boundary and keepmin=(lane&J)==0 is correct for both halves
        bstep<64, 16>(z, lane); bstep<64, 8>(z, lane); bstep<64, 4>(z, lane);
        bstep<64, 2>(z, lane);  bstep<64, 1>(z, lane);

        // ---- epilogue: row A on lanes 0..31, row B on lanes 32..63; each
        //      of the 3 stores is a contiguous 256 B wave store.
        const int half = lane >> 5;
        const int l32  = lane & 31;
        const unsigned vv = z;
        const int gi   = iA + half;               // center atom (local idx)
        const int gdst = base + gi;
        const float4 ci = half ? cB : cA;
        float w = 0.0f;
        float srcf = (float)gdst;                 // sentinel -> self-edge, w=0
        if (vv < 0x7F800000u) {
            const int j = (int)(vv & 511u);
            const float4 pj = atoms[j];
            float dot = __fadd_rn(__fadd_rn(__fmul_rn(ci.x, pj.x),
                                            __fmul_rn(ci.y, pj.y)),
                                  __fmul_rn(ci.z, pj.z));
            float d2 = __fsub_rn(__fadd_rn(ci.w, pj.w),
                                 __fmul_rn(2.0f, dot));
            d2 = fmaxf(d2, 0.0f);
            w = __fsqrt_rn(fmaxf(d2, 1e-12f));
            srcf = (float)(base + j);
        }
        const size_t eb = (size_t)gdst * 32 + (size_t)l32;
        out[eb]                     = srcf;          // src
        out[(size_t)EDGES + eb]     = (float)gdst;   // dst
        out[(size_t)EDGES * 2 + eb] = w;             // weight
    }
}

extern "C" void kernel_launch(void* const* d_in, const int* in_sizes, int n_in,
                              void* d_out, int out_size, void* d_ws, size_t ws_size,
                              hipStream_t stream) {
    (void)in_sizes; (void)n_in; (void)d_ws; (void)ws_size; (void)out_size;
    const float* pos = (const float*)d_in[0];   // [N,3] f32
    float* out       = (float*)d_out;           // [3E] f32

    RadiusInteractionGraph_73246372266582_kernel<<<dim3(4096), dim3(256), 0,
                                                   stream>>>(pos, out);
}

// Round 6
// 103.041 us; speedup vs baseline: 1.0016x; 1.0016x over previous
//

#include <hip/hip_runtime.h>

// RadiusInteractionGraph: B=128 molecules x 512 atoms, K=32 NN, cutoff 10.
// d_out is FLOAT32: [E] src ++ [E] dst ++ [E] weight, E = 128*512*32.
//
// R27 = R26 (exponent-ladder search, shared sort tail, pk-f32 build, 50us)
// with the counting phase cut 7 -> 4 passes/row on the common path:
//  (1) VERIFY PASS REMOVED: the compact's running total IS W=count(<hi);
//      the W>64 pathological check moves after the compact (repair path
//      recompacts that row -- rare, wave-uniform, straight-line).
//  (2) MANTISSA ROUNDS OFF COMMON PATH: any downward-closed window with
//      32 <= W <= 64 sorts to the IDENTICAL top-32 (keys are unique and
//      totally ordered; sort of any valid window yields the same 32
//      smallest). After the 3-round exponent binary search, hi=L[lo+1] is
//      tested-and-rejected => W>=32 guaranteed. Use it directly. If the
//      compact reports W>64 (32nd neighbor low in its octave), repair with
//      R26's exact mantissa(22,21)+refine path and recompact -- bit-exact.
//      lo outside [0,5] (dense <0.5 / sparse >=32 / sentinel) falls back to
//      the original full 10-round walk + verify + refine, as in R26.
//  (3) COMPACT ILP: 16 independent ballots first (SGPR masks), SALU prefix
//      sum, then scatter -- removes the per-chunk serial popcll->offset
//      chain (R25 lesson: keep it branchless, not branchy).
// Everything else identical to R26 (PASS): pk-f32 key build (IEEE-exact per
// half; s-2*dot == s+(-2)*dot under RN), all-VALU exchanges, 2x16+1+5
// shared-tail sort, dual-half epilogue with 256B wave stores.
// Selection semantics bit-identical to lax.top_k stable order via
// key=(d2_hi23|j); sentinel 0x7F800000|j -> pad self-edge.

constexpr int EDGES = 128 * 512 * 32;   // 2097152

typedef float f32x2 __attribute__((ext_vector_type(2)));

static __device__ __forceinline__ f32x2 pk_mul(f32x2 a, f32x2 b) {
    f32x2 d;
    asm("v_pk_mul_f32 %0, %1, %2" : "=v"(d) : "v"(a), "v"(b));
    return d;
}
static __device__ __forceinline__ f32x2 pk_add(f32x2 a, f32x2 b) {
    f32x2 d;
    asm("v_pk_add_f32 %0, %1, %2" : "=v"(d) : "v"(a), "v"(b));
    return d;
}

static __device__ __forceinline__ unsigned umin2(unsigned a, unsigned b) {
    return a < b ? a : b;
}
static __device__ __forceinline__ unsigned umax2(unsigned a, unsigned b) {
    return a > b ? a : b;
}

static __device__ __forceinline__ unsigned mbcnt64(unsigned long long m) {
    return __builtin_amdgcn_mbcnt_hi(
        (unsigned)(m >> 32),
        __builtin_amdgcn_mbcnt_lo((unsigned)m, 0u));
}

static __device__ __forceinline__ unsigned count_lt(const unsigned q[8],
                                                    unsigned C) {
    unsigned cnt = 0;
#pragma unroll
    for (int c = 0; c < 8; ++c)
        cnt += (unsigned)__popcll(__ballot(q[c] < C));
    return cnt;
}

// original greedy MSB walk over bits 30..21 (exact; rare fallback path)
static __device__ __forceinline__ unsigned full_walk(const unsigned q[8]) {
    unsigned X = 0u;
    for (int bit = 30; bit >= 21; --bit) {
        const unsigned C = X | (1u << bit);
        if (count_lt(q, C) < 32u) X = C;
    }
    return X;
}

// xor-partner fetch, all-VALU (no LDS pipe). Patterns verified (R24 PASS):
//  quad_perm 0xB1 = ^1, 0x4E = ^2, 0x1B = ^3; 0x141 row_half_mirror = ^7
//  within 8; 0x128 row_ror:8 = ^8 within 16 (+8 mod 16 == ^8).
template <int J>
static __device__ __forceinline__ unsigned xpart(unsigned v, int lane) {
    if constexpr (J == 1) {
        return (unsigned)__builtin_amdgcn_update_dpp(
            (int)v, (int)v, 0xB1, 0xF, 0xF, false);
    } else if constexpr (J == 2) {
        return (unsigned)__builtin_amdgcn_update_dpp(
            (int)v, (int)v, 0x4E, 0xF, 0xF, false);
    } else if constexpr (J == 4) {
        const int t = __builtin_amdgcn_update_dpp(
            (int)v, (int)v, 0x141, 0xF, 0xF, false);   // ^7 within 8
        return (unsigned)__builtin_amdgcn_update_dpp(
            t, t, 0x1B, 0xF, 0xF, false);              // ^3 -> net ^4
    } else if constexpr (J == 8) {
        return (unsigned)__builtin_amdgcn_update_dpp(
            (int)v, (int)v, 0x128, 0xF, 0xF, false);   // row_ror:8 = ^8
    } else if constexpr (J == 16) {
#if __has_builtin(__builtin_amdgcn_permlane16_swap)
        auto r = __builtin_amdgcn_permlane16_swap((int)v, (int)v, false, false);
        return (unsigned)((lane & 16) ? r[0] : r[1]);
#else
        return (unsigned)__shfl_xor((int)v, 16, 64);
#endif
    } else {
#if __has_builtin(__builtin_amdgcn_permlane32_swap)
        auto r = __builtin_amdgcn_permlane32_swap((int)v, (int)v, false, false);
        return (unsigned)((lane & 32) ? r[0] : r[1]);
#else
        return (unsigned)__shfl_xor((int)v, 32, 64);
#endif
    }
}

template <int K, int J>
static __device__ __forceinline__ void bstep(unsigned& v, int lane) {
    const unsigned p = xpart<J>(v, lane);
    const bool keepmin = (((lane & J) == 0) == ((lane & K) == 0));
    const unsigned mn = umin2(v, p);
    const unsigned mx = umax2(v, p);
    v = keepmin ? mn : mx;
}

// one step applied to both rows (independent chains fill stall slots;
// keepmin computed once)
template <int K, int J>
static __device__ __forceinline__ void bstep2(unsigned& a, unsigned& b,
                                              int lane) {
    const unsigned pa = xpart<J>(a, lane);
    const unsigned pb = xpart<J>(b, lane);
    const bool keepmin = (((lane & J) == 0) == ((lane & K) == 0));
    a = keepmin ? umin2(a, pa) : umax2(a, pa);
    b = keepmin ? umin2(b, pb) : umax2(b, pb);
}

// bitonic stages K=2..32 (15 steps/row), rows interleaved
static __device__ __forceinline__ void bitonic_head2(unsigned& a, unsigned& b,
                                                     int lane) {
    bstep2<2, 1>(a, b, lane);
    bstep2<4, 2>(a, b, lane);   bstep2<4, 1>(a, b, lane);
    bstep2<8, 4>(a, b, lane);   bstep2<8, 2>(a, b, lane);
    bstep2<8, 1>(a, b, lane);
    bstep2<16, 8>(a, b, lane);  bstep2<16, 4>(a, b, lane);
    bstep2<16, 2>(a, b, lane);  bstep2<16, 1>(a, b, lane);
    bstep2<32, 16>(a, b, lane); bstep2<32, 8>(a, b, lane);
    bstep2<32, 4>(a, b, lane);  bstep2<32, 2>(a, b, lane);
    bstep2<32, 1>(a, b, lane);
}

__global__ __launch_bounds__(256)
void RadiusInteractionGraph_73246372266582_kernel(const float* __restrict__ pos,
                                                  float* __restrict__ out) {
    __shared__ float4 atoms[512];        // x, y, z, |p|^2
    __shared__ unsigned wbuf[4][2][64];  // per-wave, per-interleaved-row

    const int tid     = threadIdx.x;
    const int b       = blockIdx.x >> 5;          // 32 blocks per molecule
    const int rowbase = (blockIdx.x & 31) * 16;   // 16 rows per block
    const int base    = b * 512;

    for (int a = tid; a < 512; a += 256) {
        float x = pos[(base + a) * 3 + 0];
        float y = pos[(base + a) * 3 + 1];
        float z = pos[(base + a) * 3 + 2];
        // np: sum(p*p) = (x*x + y*y) + z*z, sequential f32, no fma
        float sq = __fadd_rn(__fadd_rn(__fmul_rn(x, x), __fmul_rn(y, y)),
                             __fmul_rn(z, z));
        atoms[a] = make_float4(x, y, z, sq);
    }
    __syncthreads();

    const int wave = tid >> 6;
    const int lane = tid & 63;

    const f32x2 NEG2 = {-2.0f, -2.0f};

    for (int rp = 0; rp < 2; ++rp) {
        const int iA = rowbase + wave * 4 + rp * 2;
        const int iB = iA + 1;
        const float4 cA = atoms[iA];
        const float4 cB = atoms[iB];
        const f32x2 CX = {cA.x, cB.x};
        const f32x2 CY = {cA.y, cB.y};
        const f32x2 CZ = {cA.z, cB.z};
        const f32x2 CW = {cA.w, cB.w};

        // ---- build 8 UNIQUE keys per lane, rows A,B packed in pk-f32 ----
        unsigned qA[8], qB[8];
#pragma unroll
        for (int c = 0; c < 8; ++c) {
            const int j = c * 64 + lane;
            const float4 pj = atoms[j];           // one ds_read_b128, shared
            const f32x2 px = {pj.x, pj.x};
            const f32x2 py = {pj.y, pj.y};
            const f32x2 pz = {pj.z, pj.z};
            const f32x2 pw = {pj.w, pj.w};
            // np einsum order: ((xi*xj + yi*yj) + zi*zj), exact per half
            const f32x2 txx = pk_mul(CX, px);
            const f32x2 tyy = pk_mul(CY, py);
            const f32x2 sxy = pk_add(txx, tyy);
            const f32x2 tzz = pk_mul(CZ, pz);
            const f32x2 dot = pk_add(sxy, tzz);
            // d2 = (ci.w + pj.w) - 2*dot == (ci.w + pj.w) + (-2)*dot exactly
            const f32x2 sw  = pk_add(CW, pw);
            const f32x2 m2  = pk_mul(dot, NEG2);
            const f32x2 d2p = pk_add(sw, m2);
            const float d2A = fmaxf(d2p.x, 0.0f);
            const float d2B = fmaxf(d2p.y, 0.0f);
            qA[c] = ((j != iA) && (d2A <= 100.0f))
                        ? ((__float_as_uint(d2A) & 0xFFFFFE00u) | (unsigned)j)
                        : (0x7F800000u | (unsigned)j);
            qB[c] = ((j != iB) && (d2B <= 100.0f))
                        ? ((__float_as_uint(d2B) & 0xFFFFFE00u) | (unsigned)j)
                        : (0x7F800000u | (unsigned)j);
        }

        // ---- exponent binary search: 3 rounds over L[i]=(0x7E+i)<<23 ----
        // (d2 thresholds 0.5,1,2,4,8,16,32). Largest i with count(<L[i])<32.
        int loA = -1, hiiA = 7, loB = -1, hiiB = 7;
#pragma unroll
        for (int r = 0; r < 3; ++r) {
            const int mA = (loA + hiiA) >> 1;
            const int mB = (loB + hiiB) >> 1;
            const unsigned CA = (unsigned)((0x7E + mA) << 23);
            const unsigned CB = (unsigned)((0x7E + mB) << 23);
            unsigned ca = 0, cb = 0;
#pragma unroll
            for (int c = 0; c < 8; ++c) {
                ca += (unsigned)__popcll(__ballot(qA[c] < CA));
                cb += (unsigned)__popcll(__ballot(qB[c] < CB));
            }
            if (ca < 32u) loA = mA; else hiiA = mA;
            if (cb < 32u) loB = mB; else hiiB = mB;
        }

        // ---- window bound: common path hi = L[lo+1] (tested-rejected =>
        //      count >= 32). lo outside [0,5]: exact full-walk fallback.
        const bool okA = (loA >= 0) && (loA < 6);
        const bool okB = (loB >= 0) && (loB < 6);
        unsigned hiA, hiB;
        if (okA) {
            hiA = (unsigned)((0x7F + loA) << 23);   // L[loA+1]
        } else {
            unsigned X = full_walk(qA);
            hiA = X + (1u << 21);
            if (count_lt(qA, hiA) > 64u) {          // pathological refine
                for (int bit = 20; bit >= 0; --bit) {
                    const unsigned C = X | (1u << bit);
                    if (count_lt(qA, C) < 32u) X = C;
                }
                hiA = X + 1u;
            }
        }
        if (okB) {
            hiB = (unsigned)((0x7F + loB) << 23);
        } else {
            unsigned X = full_walk(qB);
            hiB = X + (1u << 21);
            if (count_lt(qB, hiB) > 64u) {
                for (int bit = 20; bit >= 0; --bit) {
                    const unsigned C = X | (1u << bit);
                    if (count_lt(qB, C) < 32u) X = C;
                }
                hiB = X + 1u;
            }
        }

        // ---- compact (ballots -> SGPR masks, prefix, scatter); t == W ----
        unsigned long long mskA[8], mskB[8];
#pragma unroll
        for (int c = 0; c < 8; ++c) {
            mskA[c] = __ballot(qA[c] < hiA);
            mskB[c] = __ballot(qB[c] < hiB);
        }
        unsigned tA = 0, tB = 0, offA[8], offB[8];
#pragma unroll
        for (int c = 0; c < 8; ++c) {
            offA[c] = tA; tA += (unsigned)__popcll(mskA[c]);
            offB[c] = tB; tB += (unsigned)__popcll(mskB[c]);
        }
        wbuf[wave][0][lane] = 0xFFFFFFFFu;
        wbuf[wave][1][lane] = 0xFFFFFFFFu;
#pragma unroll
        for (int c = 0; c < 8; ++c) {
            if (qA[c] < hiA) wbuf[wave][0][offA[c] + mbcnt64(mskA[c])] = qA[c];
            if (qB[c] < hiB) wbuf[wave][1][offB[c] + mbcnt64(mskB[c])] = qB[c];
        }

        // ---- repair (W>64 on common path): exact mantissa+refine, redo ----
        if (okA && tA > 64u) {
            unsigned X = (unsigned)((0x7E + loA) << 23);   // L[loA], count<32
            for (int bit = 22; bit >= 21; --bit) {
                const unsigned C = X | (1u << bit);
                if (count_lt(qA, C) < 32u) X = C;
            }
            hiA = X + (1u << 21);
            if (count_lt(qA, hiA) > 64u) {
                for (int bit = 20; bit >= 0; --bit) {
                    const unsigned C = X | (1u << bit);
                    if (count_lt(qA, C) < 32u) X = C;
                }
                hiA = X + 1u;
            }
            wbuf[wave][0][lane] = 0xFFFFFFFFu;
            unsigned t = 0;
#pragma unroll
            for (int c = 0; c < 8; ++c) {
                const bool s = (qA[c] < hiA);
                const unsigned long long m = __ballot(s);
                if (s) wbuf[wave][0][t + mbcnt64(m)] = qA[c];
                t += (unsigned)__popcll(m);
            }
        }
        if (okB && tB > 64u) {
            unsigned X = (unsigned)((0x7E + loB) << 23);
            for (int bit = 22; bit >= 21; --bit) {
                const unsigned C = X | (1u << bit);
                if (count_lt(qB, C) < 32u) X = C;
            }
            hiB = X + (1u << 21);
            if (count_lt(qB, hiB) > 64u) {
                for (int bit = 20; bit >= 0; --bit) {
                    const unsigned C = X | (1u << bit);
                    if (count_lt(qB, C) < 32u) X = C;
                }
                hiB = X + 1u;
            }
            wbuf[wave][1][lane] = 0xFFFFFFFFu;
            unsigned t = 0;
#pragma unroll
            for (int c = 0; c < 8; ++c) {
                const bool s = (qB[c] < hiB);
                const unsigned long long m = __ballot(s);
                if (s) wbuf[wave][1][t + mbcnt64(m)] = qB[c];
                t += (unsigned)__popcll(m);
            }
        }

        unsigned vA = wbuf[wave][0][lane];   // per-wave LDS is in-order
        unsigned vB = wbuf[wave][1][lane];

        // ---- sort: heads + half-cleaners per row, then ONE shared tail ----
        bitonic_head2(vA, vB, lane);         // K=2..32, both rows
        bstep2<64, 32>(vA, vB, lane);        // half-cleaner: 32 smallest low
        // pack: A-low stays lanes 0-31; B-low -> lanes 32-63 (this permlane
        // replaces the old epilogue swap)
        unsigned z = (lane & 32) ? xpart<32>(vB, lane) : vA;
        // final ascending merge of each bitonic 32-half; strides never cross
        // the 32-boundary and keepmin=(lane&J)==0 is correct for both halves
        bstep<64, 16>(z, lane); bstep<64, 8>(z, lane); bstep<64, 4>(z, lane);
        bstep<64, 2>(z, lane);  bstep<64, 1>(z, lane);

        // ---- epilogue: row A on lanes 0..31, row B on lanes 32..63; each
        //      of the 3 stores is a contiguous 256 B wave store.
        const int half = lane >> 5;
        const int l32  = lane & 31;
        const unsigned vv = z;
        const int gi   = iA + half;               // center atom (local idx)
        const int gdst = base + gi;
        const float4 ci = half ? cB : cA;
        float w = 0.0f;
        float srcf = (float)gdst;                 // sentinel -> self-edge, w=0
        if (vv < 0x7F800000u) {
            const int j = (int)(vv & 511u);
            const float4 pj = atoms[j];
            float dot = __fadd_rn(__fadd_rn(__fmul_rn(ci.x, pj.x),
                                            __fmul_rn(ci.y, pj.y)),
                                  __fmul_rn(ci.z, pj.z));
            float d2 = __fsub_rn(__fadd_rn(ci.w, pj.w),
                                 __fmul_rn(2.0f, dot));
            d2 = fmaxf(d2, 0.0f);
            w = __fsqrt_rn(fmaxf(d2, 1e-12f));
            srcf = (float)(base + j);
        }
        const size_t eb = (size_t)gdst * 32 + (size_t)l32;
        out[eb]                     = srcf;          // src
        out[(size_t)EDGES + eb]     = (float)gdst;   // dst
        out[(size_t)EDGES * 2 + eb] = w;             // weight
    }
}

extern "C" void kernel_launch(void* const* d_in, const int* in_sizes, int n_in,
                              void* d_out, int out_size, void* d_ws, size_t ws_size,
                              hipStream_t stream) {
    (void)in_sizes; (void)n_in; (void)d_ws; (void)ws_size; (void)out_size;
    const float* pos = (const float*)d_in[0];   // [N,3] f32
    float* out       = (float*)d_out;           // [3E] f32

    RadiusInteractionGraph_73246372266582_kernel<<<dim3(4096), dim3(256), 0,
                                                   stream>>>(pos, out);
}

// Round 7
// 98.067 us; speedup vs baseline: 1.0524x; 1.0507x over previous
//

#include <hip/hip_runtime.h>

// RadiusInteractionGraph: B=128 molecules x 512 atoms, K=32 NN, cutoff 10.
// d_out is FLOAT32: [E] src ++ [E] dst ++ [E] weight, E = 128*512*32.
//
// R28 = R27 algorithm UNCHANGED (exponent binary search, direct-window
// compact w/ post-hoc repair, pk-f32 build, shared sort tail — PASS @50.6us)
// with the GEOMETRY changed: one row-pair per wave (rp loop removed),
// 8192 blocks x 256 threads, 8 rows/block (64 blocks/molecule).
// Rationale (R24->R27 ledger): three consecutive VALU op cuts (-15% issue)
// never moved the 48-50us wall -> NOT issue-bound; latency-bound on the
// per-wave serial path (build->search->compact->sort->epilogue, x2 per
// wave). R22 showed wall tracks resident-wave cover (occupancy halving ->
// +22% wall). So: halve the per-wave serial path, double block-level
// parallelism, shrink the drain tail. Extra 512-atom fills stay L2-hot.
// Selection semantics bit-identical to lax.top_k stable order via
// key=(d2_hi23|j); exact __f*_rn np arithmetic (pk-f32 IEEE-exact per half;
// s-2*dot == s+(-2)*dot under RN); sentinel 0x7F800000|j -> pad self-edge;
// repair/fallback paths exact (R19/R26/R27 lineage).

constexpr int EDGES = 128 * 512 * 32;   // 2097152

typedef float f32x2 __attribute__((ext_vector_type(2)));

static __device__ __forceinline__ f32x2 pk_mul(f32x2 a, f32x2 b) {
    f32x2 d;
    asm("v_pk_mul_f32 %0, %1, %2" : "=v"(d) : "v"(a), "v"(b));
    return d;
}
static __device__ __forceinline__ f32x2 pk_add(f32x2 a, f32x2 b) {
    f32x2 d;
    asm("v_pk_add_f32 %0, %1, %2" : "=v"(d) : "v"(a), "v"(b));
    return d;
}

static __device__ __forceinline__ unsigned umin2(unsigned a, unsigned b) {
    return a < b ? a : b;
}
static __device__ __forceinline__ unsigned umax2(unsigned a, unsigned b) {
    return a > b ? a : b;
}

static __device__ __forceinline__ unsigned mbcnt64(unsigned long long m) {
    return __builtin_amdgcn_mbcnt_hi(
        (unsigned)(m >> 32),
        __builtin_amdgcn_mbcnt_lo((unsigned)m, 0u));
}

static __device__ __forceinline__ unsigned count_lt(const unsigned q[8],
                                                    unsigned C) {
    unsigned cnt = 0;
#pragma unroll
    for (int c = 0; c < 8; ++c)
        cnt += (unsigned)__popcll(__ballot(q[c] < C));
    return cnt;
}

// original greedy MSB walk over bits 30..21 (exact; rare fallback path)
static __device__ __forceinline__ unsigned full_walk(const unsigned q[8]) {
    unsigned X = 0u;
    for (int bit = 30; bit >= 21; --bit) {
        const unsigned C = X | (1u << bit);
        if (count_lt(q, C) < 32u) X = C;
    }
    return X;
}

// xor-partner fetch, all-VALU (no LDS pipe). Patterns verified (R24 PASS):
//  quad_perm 0xB1 = ^1, 0x4E = ^2, 0x1B = ^3; 0x141 row_half_mirror = ^7
//  within 8; 0x128 row_ror:8 = ^8 within 16 (+8 mod 16 == ^8).
template <int J>
static __device__ __forceinline__ unsigned xpart(unsigned v, int lane) {
    if constexpr (J == 1) {
        return (unsigned)__builtin_amdgcn_update_dpp(
            (int)v, (int)v, 0xB1, 0xF, 0xF, false);
    } else if constexpr (J == 2) {
        return (unsigned)__builtin_amdgcn_update_dpp(
            (int)v, (int)v, 0x4E, 0xF, 0xF, false);
    } else if constexpr (J == 4) {
        const int t = __builtin_amdgcn_update_dpp(
            (int)v, (int)v, 0x141, 0xF, 0xF, false);   // ^7 within 8
        return (unsigned)__builtin_amdgcn_update_dpp(
            t, t, 0x1B, 0xF, 0xF, false);              // ^3 -> net ^4
    } else if constexpr (J == 8) {
        return (unsigned)__builtin_amdgcn_update_dpp(
            (int)v, (int)v, 0x128, 0xF, 0xF, false);   // row_ror:8 = ^8
    } else if constexpr (J == 16) {
#if __has_builtin(__builtin_amdgcn_permlane16_swap)
        auto r = __builtin_amdgcn_permlane16_swap((int)v, (int)v, false, false);
        return (unsigned)((lane & 16) ? r[0] : r[1]);
#else
        return (unsigned)__shfl_xor((int)v, 16, 64);
#endif
    } else {
#if __has_builtin(__builtin_amdgcn_permlane32_swap)
        auto r = __builtin_amdgcn_permlane32_swap((int)v, (int)v, false, false);
        return (unsigned)((lane & 32) ? r[0] : r[1]);
#else
        return (unsigned)__shfl_xor((int)v, 32, 64);
#endif
    }
}

template <int K, int J>
static __device__ __forceinline__ void bstep(unsigned& v, int lane) {
    const unsigned p = xpart<J>(v, lane);
    const bool keepmin = (((lane & J) == 0) == ((lane & K) == 0));
    const unsigned mn = umin2(v, p);
    const unsigned mx = umax2(v, p);
    v = keepmin ? mn : mx;
}

// one step applied to both rows (independent chains fill stall slots;
// keepmin computed once)
template <int K, int J>
static __device__ __forceinline__ void bstep2(unsigned& a, unsigned& b,
                                              int lane) {
    const unsigned pa = xpart<J>(a, lane);
    const unsigned pb = xpart<J>(b, lane);
    const bool keepmin = (((lane & J) == 0) == ((lane & K) == 0));
    a = keepmin ? umin2(a, pa) : umax2(a, pa);
    b = keepmin ? umin2(b, pb) : umax2(b, pb);
}

// bitonic stages K=2..32 (15 steps/row), rows interleaved
static __device__ __forceinline__ void bitonic_head2(unsigned& a, unsigned& b,
                                                     int lane) {
    bstep2<2, 1>(a, b, lane);
    bstep2<4, 2>(a, b, lane);   bstep2<4, 1>(a, b, lane);
    bstep2<8, 4>(a, b, lane);   bstep2<8, 2>(a, b, lane);
    bstep2<8, 1>(a, b, lane);
    bstep2<16, 8>(a, b, lane);  bstep2<16, 4>(a, b, lane);
    bstep2<16, 2>(a, b, lane);  bstep2<16, 1>(a, b, lane);
    bstep2<32, 16>(a, b, lane); bstep2<32, 8>(a, b, lane);
    bstep2<32, 4>(a, b, lane);  bstep2<32, 2>(a, b, lane);
    bstep2<32, 1>(a, b, lane);
}

__global__ __launch_bounds__(256)
void RadiusInteractionGraph_73246372266582_kernel(const float* __restrict__ pos,
                                                  float* __restrict__ out) {
    __shared__ float4 atoms[512];        // x, y, z, |p|^2
    __shared__ unsigned wbuf[4][2][64];  // per-wave, per-row window buffer

    const int tid     = threadIdx.x;
    const int b       = blockIdx.x >> 6;          // 64 blocks per molecule
    const int rowbase = (blockIdx.x & 63) * 8;    // 8 rows per block
    const int base    = b * 512;

    for (int a = tid; a < 512; a += 256) {
        float x = pos[(base + a) * 3 + 0];
        float y = pos[(base + a) * 3 + 1];
        float z = pos[(base + a) * 3 + 2];
        // np: sum(p*p) = (x*x + y*y) + z*z, sequential f32, no fma
        float sq = __fadd_rn(__fadd_rn(__fmul_rn(x, x), __fmul_rn(y, y)),
                             __fmul_rn(z, z));
        atoms[a] = make_float4(x, y, z, sq);
    }
    __syncthreads();

    const int wave = tid >> 6;
    const int lane = tid & 63;

    const f32x2 NEG2 = {-2.0f, -2.0f};

    const int iA = rowbase + wave * 2;            // ONE row pair per wave
    const int iB = iA + 1;
    const float4 cA = atoms[iA];
    const float4 cB = atoms[iB];
    const f32x2 CX = {cA.x, cB.x};
    const f32x2 CY = {cA.y, cB.y};
    const f32x2 CZ = {cA.z, cB.z};
    const f32x2 CW = {cA.w, cB.w};

    // ---- build 8 UNIQUE keys per lane, rows A,B packed in pk-f32 ----
    unsigned qA[8], qB[8];
#pragma unroll
    for (int c = 0; c < 8; ++c) {
        const int j = c * 64 + lane;
        const float4 pj = atoms[j];               // one ds_read_b128, shared
        const f32x2 px = {pj.x, pj.x};
        const f32x2 py = {pj.y, pj.y};
        const f32x2 pz = {pj.z, pj.z};
        const f32x2 pw = {pj.w, pj.w};
        // np einsum order: ((xi*xj + yi*yj) + zi*zj), exact per half
        const f32x2 txx = pk_mul(CX, px);
        const f32x2 tyy = pk_mul(CY, py);
        const f32x2 sxy = pk_add(txx, tyy);
        const f32x2 tzz = pk_mul(CZ, pz);
        const f32x2 dot = pk_add(sxy, tzz);
        // d2 = (ci.w + pj.w) - 2*dot == (ci.w + pj.w) + (-2)*dot exactly
        const f32x2 sw  = pk_add(CW, pw);
        const f32x2 m2  = pk_mul(dot, NEG2);
        const f32x2 d2p = pk_add(sw, m2);
        const float d2A = fmaxf(d2p.x, 0.0f);
        const float d2B = fmaxf(d2p.y, 0.0f);
        qA[c] = ((j != iA) && (d2A <= 100.0f))
                    ? ((__float_as_uint(d2A) & 0xFFFFFE00u) | (unsigned)j)
                    : (0x7F800000u | (unsigned)j);
        qB[c] = ((j != iB) && (d2B <= 100.0f))
                    ? ((__float_as_uint(d2B) & 0xFFFFFE00u) | (unsigned)j)
                    : (0x7F800000u | (unsigned)j);
    }

    // ---- exponent binary search: 3 rounds over L[i]=(0x7E+i)<<23 ----
    // (d2 thresholds 0.5,1,2,4,8,16,32). Largest i with count(<L[i])<32.
    int loA = -1, hiiA = 7, loB = -1, hiiB = 7;
#pragma unroll
    for (int r = 0; r < 3; ++r) {
        const int mA = (loA + hiiA) >> 1;
        const int mB = (loB + hiiB) >> 1;
        const unsigned CA = (unsigned)((0x7E + mA) << 23);
        const unsigned CB = (unsigned)((0x7E + mB) << 23);
        unsigned ca = 0, cb = 0;
#pragma unroll
        for (int c = 0; c < 8; ++c) {
            ca += (unsigned)__popcll(__ballot(qA[c] < CA));
            cb += (unsigned)__popcll(__ballot(qB[c] < CB));
        }
        if (ca < 32u) loA = mA; else hiiA = mA;
        if (cb < 32u) loB = mB; else hiiB = mB;
    }

    // ---- window bound: common path hi = L[lo+1] (tested-rejected =>
    //      count >= 32). lo outside [0,5]: exact full-walk fallback.
    const bool okA = (loA >= 0) && (loA < 6);
    const bool okB = (loB >= 0) && (loB < 6);
    unsigned hiA, hiB;
    if (okA) {
        hiA = (unsigned)((0x7F + loA) << 23);     // L[loA+1]
    } else {
        unsigned X = full_walk(qA);
        hiA = X + (1u << 21);
        if (count_lt(qA, hiA) > 64u) {            // pathological refine
            for (int bit = 20; bit >= 0; --bit) {
                const unsigned C = X | (1u << bit);
                if (count_lt(qA, C) < 32u) X = C;
            }
            hiA = X + 1u;
        }
    }
    if (okB) {
        hiB = (unsigned)((0x7F + loB) << 23);
    } else {
        unsigned X = full_walk(qB);
        hiB = X + (1u << 21);
        if (count_lt(qB, hiB) > 64u) {
            for (int bit = 20; bit >= 0; --bit) {
                const unsigned C = X | (1u << bit);
                if (count_lt(qB, C) < 32u) X = C;
            }
            hiB = X + 1u;
        }
    }

    // ---- compact (ballots -> SGPR masks, prefix, scatter); t == W ----
    unsigned long long mskA[8], mskB[8];
#pragma unroll
    for (int c = 0; c < 8; ++c) {
        mskA[c] = __ballot(qA[c] < hiA);
        mskB[c] = __ballot(qB[c] < hiB);
    }
    unsigned tA = 0, tB = 0, offA[8], offB[8];
#pragma unroll
    for (int c = 0; c < 8; ++c) {
        offA[c] = tA; tA += (unsigned)__popcll(mskA[c]);
        offB[c] = tB; tB += (unsigned)__popcll(mskB[c]);
    }
    wbuf[wave][0][lane] = 0xFFFFFFFFu;
    wbuf[wave][1][lane] = 0xFFFFFFFFu;
#pragma unroll
    for (int c = 0; c < 8; ++c) {
        if (qA[c] < hiA) wbuf[wave][0][offA[c] + mbcnt64(mskA[c])] = qA[c];
        if (qB[c] < hiB) wbuf[wave][1][offB[c] + mbcnt64(mskB[c])] = qB[c];
    }

    // ---- repair (W>64 on common path): exact mantissa+refine, redo ----
    if (okA && tA > 64u) {
        unsigned X = (unsigned)((0x7E + loA) << 23);   // L[loA], count<32
        for (int bit = 22; bit >= 21; --bit) {
            const unsigned C = X | (1u << bit);
            if (count_lt(qA, C) < 32u) X = C;
        }
        hiA = X + (1u << 21);
        if (count_lt(qA, hiA) > 64u) {
            for (int bit = 20; bit >= 0; --bit) {
                const unsigned C = X | (1u << bit);
                if (count_lt(qA, C) < 32u) X = C;
            }
            hiA = X + 1u;
        }
        wbuf[wave][0][lane] = 0xFFFFFFFFu;
        unsigned t = 0;
#pragma unroll
        for (int c = 0; c < 8; ++c) {
            const bool s = (qA[c] < hiA);
            const unsigned long long m = __ballot(s);
            if (s) wbuf[wave][0][t + mbcnt64(m)] = qA[c];
            t += (unsigned)__popcll(m);
        }
    }
    if (okB && tB > 64u) {
        unsigned X = (unsigned)((0x7E + loB) << 23);
        for (int bit = 22; bit >= 21; --bit) {
            const unsigned C = X | (1u << bit);
            if (count_lt(qB, C) < 32u) X = C;
        }
        hiB = X + (1u << 21);
        if (count_lt(qB, hiB) > 64u) {
            for (int bit = 20; bit >= 0; --bit) {
                const unsigned C = X | (1u << bit);
                if (count_lt(qB, C) < 32u) X = C;
            }
            hiB = X + 1u;
        }
        wbuf[wave][1][lane] = 0xFFFFFFFFu;
        unsigned t = 0;
#pragma unroll
        for (int c = 0; c < 8; ++c) {
            const bool s = (qB[c] < hiB);
            const unsigned long long m = __ballot(s);
            if (s) wbuf[wave][1][t + mbcnt64(m)] = qB[c];
            t += (unsigned)__popcll(m);
        }
    }

    unsigned vA = wbuf[wave][0][lane];   // per-wave LDS is in-order
    unsigned vB = wbuf[wave][1][lane];

    // ---- sort: heads + half-cleaners per row, then ONE shared tail ----
    bitonic_head2(vA, vB, lane);         // K=2..32, both rows
    bstep2<64, 32>(vA, vB, lane);        // half-cleaner: 32 smallest low
    // pack: A-low stays lanes 0-31; B-low -> lanes 32-63
    unsigned z = (lane & 32) ? xpart<32>(vB, lane) : vA;
    // final ascending merge of each bitonic 32-half; strides never cross
    // the 32-boundary and keepmin=(lane&J)==0 is correct for both halves
    bstep<64, 16>(z, lane); bstep<64, 8>(z, lane); bstep<64, 4>(z, lane);
    bstep<64, 2>(z, lane);  bstep<64, 1>(z, lane);

    // ---- epilogue: row A on lanes 0..31, row B on lanes 32..63; each
    //      of the 3 stores is a contiguous 256 B wave store.
    const int half = lane >> 5;
    const int l32  = lane & 31;
    const unsigned vv = z;
    const int gi   = iA + half;               // center atom (local idx)
    const int gdst = base + gi;
    const float4 ci = half ? cB : cA;
    float w = 0.0f;
    float srcf = (float)gdst;                 // sentinel -> self-edge, w=0
    if (vv < 0x7F800000u) {
        const int j = (int)(vv & 511u);
        const float4 pj = atoms[j];
        float dot = __fadd_rn(__fadd_rn(__fmul_rn(ci.x, pj.x),
                                        __fmul_rn(ci.y, pj.y)),
                              __fmul_rn(ci.z, pj.z));
        float d2 = __fsub_rn(__fadd_rn(ci.w, pj.w),
                             __fmul_rn(2.0f, dot));
        d2 = fmaxf(d2, 0.0f);
        w = __fsqrt_rn(fmaxf(d2, 1e-12f));
        srcf = (float)(base + j);
    }
    const size_t eb = (size_t)gdst * 32 + (size_t)l32;
    out[eb]                     = srcf;          // src
    out[(size_t)EDGES + eb]     = (float)gdst;   // dst
    out[(size_t)EDGES * 2 + eb] = w;             // weight
}

extern "C" void kernel_launch(void* const* d_in, const int* in_sizes, int n_in,
                              void* d_out, int out_size, void* d_ws, size_t ws_size,
                              hipStream_t stream) {
    (void)in_sizes; (void)n_in; (void)d_ws; (void)ws_size; (void)out_size;
    const float* pos = (const float*)d_in[0];   // [N,3] f32
    float* out       = (float*)d_out;           // [3E] f32

    RadiusInteractionGraph_73246372266582_kernel<<<dim3(8192), dim3(256), 0,
                                                   stream>>>(pos, out);
}

// Round 8
// 97.687 us; speedup vs baseline: 1.0565x; 1.0039x over previous
//

#include <hip/hip_runtime.h>

// RadiusInteractionGraph: B=128 molecules x 512 atoms, K=32 NN, cutoff 10.
// d_out is FLOAT32: [E] src ++ [E] dst ++ [E] weight, E = 128*512*32.
//
// R29 = R28 (one row-pair per wave, 8192 blocks x 256 thr, exponent binary
// search + direct-window compact + shared sort tail — PASS @47.0us, occ 63%,
// VGPR 32) with the pk-f32 build fed by a PRE-DUPLICATED LDS layout:
//   atoms_xy[a] = {x,x,y,y};  atoms_zw[a] = {z,z,|p|^2,|p|^2}
// Two separate stride-16B arrays keep the canonical conflict-free b128
// pattern (one 32B-stride array would 4-way-conflict every build read).
// Each chunk: 2x ds_read_b128 whose register pairs ARE the pk operands —
// removes the 4 broadcast v_movs/chunk (~32 VALU/wave, ~7% of issue) that
// {pj.x,pj.x} packing forced. LDS 10->18KB/block still fits 8 blocks/CU
// (147KB < 160KB) -> occupancy unchanged. Extra LDS reads ride the idle
// LDS pipe. Rejected: search-mask reuse for the compact (scatter still
// needs the same v_cmp per chunk -> net zero VALU saving).
// Selection semantics bit-identical to lax.top_k stable order via
// key=(d2_hi23|j); exact __f*_rn np arithmetic (pk-f32 IEEE-exact per half;
// s-2*dot == s+(-2)*dot under RN); sentinel 0x7F800000|j -> pad self-edge;
// repair/fallback paths exact (R19/R26/R27 lineage).

constexpr int EDGES = 128 * 512 * 32;   // 2097152

typedef float f32x2 __attribute__((ext_vector_type(2)));

static __device__ __forceinline__ f32x2 pk_mul(f32x2 a, f32x2 b) {
    f32x2 d;
    asm("v_pk_mul_f32 %0, %1, %2" : "=v"(d) : "v"(a), "v"(b));
    return d;
}
static __device__ __forceinline__ f32x2 pk_add(f32x2 a, f32x2 b) {
    f32x2 d;
    asm("v_pk_add_f32 %0, %1, %2" : "=v"(d) : "v"(a), "v"(b));
    return d;
}

static __device__ __forceinline__ unsigned umin2(unsigned a, unsigned b) {
    return a < b ? a : b;
}
static __device__ __forceinline__ unsigned umax2(unsigned a, unsigned b) {
    return a > b ? a : b;
}

static __device__ __forceinline__ unsigned mbcnt64(unsigned long long m) {
    return __builtin_amdgcn_mbcnt_hi(
        (unsigned)(m >> 32),
        __builtin_amdgcn_mbcnt_lo((unsigned)m, 0u));
}

static __device__ __forceinline__ unsigned count_lt(const unsigned q[8],
                                                    unsigned C) {
    unsigned cnt = 0;
#pragma unroll
    for (int c = 0; c < 8; ++c)
        cnt += (unsigned)__popcll(__ballot(q[c] < C));
    return cnt;
}

// original greedy MSB walk over bits 30..21 (exact; rare fallback path)
static __device__ __forceinline__ unsigned full_walk(const unsigned q[8]) {
    unsigned X = 0u;
    for (int bit = 30; bit >= 21; --bit) {
        const unsigned C = X | (1u << bit);
        if (count_lt(q, C) < 32u) X = C;
    }
    return X;
}

// xor-partner fetch, all-VALU (no LDS pipe). Patterns verified (R24 PASS):
//  quad_perm 0xB1 = ^1, 0x4E = ^2, 0x1B = ^3; 0x141 row_half_mirror = ^7
//  within 8; 0x128 row_ror:8 = ^8 within 16 (+8 mod 16 == ^8).
template <int J>
static __device__ __forceinline__ unsigned xpart(unsigned v, int lane) {
    if constexpr (J == 1) {
        return (unsigned)__builtin_amdgcn_update_dpp(
            (int)v, (int)v, 0xB1, 0xF, 0xF, false);
    } else if constexpr (J == 2) {
        return (unsigned)__builtin_amdgcn_update_dpp(
            (int)v, (int)v, 0x4E, 0xF, 0xF, false);
    } else if constexpr (J == 4) {
        const int t = __builtin_amdgcn_update_dpp(
            (int)v, (int)v, 0x141, 0xF, 0xF, false);   // ^7 within 8
        return (unsigned)__builtin_amdgcn_update_dpp(
            t, t, 0x1B, 0xF, 0xF, false);              // ^3 -> net ^4
    } else if constexpr (J == 8) {
        return (unsigned)__builtin_amdgcn_update_dpp(
            (int)v, (int)v, 0x128, 0xF, 0xF, false);   // row_ror:8 = ^8
    } else if constexpr (J == 16) {
#if __has_builtin(__builtin_amdgcn_permlane16_swap)
        auto r = __builtin_amdgcn_permlane16_swap((int)v, (int)v, false, false);
        return (unsigned)((lane & 16) ? r[0] : r[1]);
#else
        return (unsigned)__shfl_xor((int)v, 16, 64);
#endif
    } else {
#if __has_builtin(__builtin_amdgcn_permlane32_swap)
        auto r = __builtin_amdgcn_permlane32_swap((int)v, (int)v, false, false);
        return (unsigned)((lane & 32) ? r[0] : r[1]);
#else
        return (unsigned)__shfl_xor((int)v, 32, 64);
#endif
    }
}

template <int K, int J>
static __device__ __forceinline__ void bstep(unsigned& v, int lane) {
    const unsigned p = xpart<J>(v, lane);
    const bool keepmin = (((lane & J) == 0) == ((lane & K) == 0));
    const unsigned mn = umin2(v, p);
    const unsigned mx = umax2(v, p);
    v = keepmin ? mn : mx;
}

// one step applied to both rows (independent chains fill stall slots;
// keepmin computed once)
template <int K, int J>
static __device__ __forceinline__ void bstep2(unsigned& a, unsigned& b,
                                              int lane) {
    const unsigned pa = xpart<J>(a, lane);
    const unsigned pb = xpart<J>(b, lane);
    const bool keepmin = (((lane & J) == 0) == ((lane & K) == 0));
    a = keepmin ? umin2(a, pa) : umax2(a, pa);
    b = keepmin ? umin2(b, pb) : umax2(b, pb);
}

// bitonic stages K=2..32 (15 steps/row), rows interleaved
static __device__ __forceinline__ void bitonic_head2(unsigned& a, unsigned& b,
                                                     int lane) {
    bstep2<2, 1>(a, b, lane);
    bstep2<4, 2>(a, b, lane);   bstep2<4, 1>(a, b, lane);
    bstep2<8, 4>(a, b, lane);   bstep2<8, 2>(a, b, lane);
    bstep2<8, 1>(a, b, lane);
    bstep2<16, 8>(a, b, lane);  bstep2<16, 4>(a, b, lane);
    bstep2<16, 2>(a, b, lane);  bstep2<16, 1>(a, b, lane);
    bstep2<32, 16>(a, b, lane); bstep2<32, 8>(a, b, lane);
    bstep2<32, 4>(a, b, lane);  bstep2<32, 2>(a, b, lane);
    bstep2<32, 1>(a, b, lane);
}

__global__ __launch_bounds__(256)
void RadiusInteractionGraph_73246372266582_kernel(const float* __restrict__ pos,
                                                  float* __restrict__ out) {
    __shared__ float4 atoms_xy[512];     // {x, x, y, y}
    __shared__ float4 atoms_zw[512];     // {z, z, |p|^2, |p|^2}
    __shared__ unsigned wbuf[4][2][64];  // per-wave, per-row window buffer

    const int tid     = threadIdx.x;
    const int b       = blockIdx.x >> 6;          // 64 blocks per molecule
    const int rowbase = (blockIdx.x & 63) * 8;    // 8 rows per block
    const int base    = b * 512;

    for (int a = tid; a < 512; a += 256) {
        float x = pos[(base + a) * 3 + 0];
        float y = pos[(base + a) * 3 + 1];
        float z = pos[(base + a) * 3 + 2];
        // np: sum(p*p) = (x*x + y*y) + z*z, sequential f32, no fma
        float sq = __fadd_rn(__fadd_rn(__fmul_rn(x, x), __fmul_rn(y, y)),
                             __fmul_rn(z, z));
        atoms_xy[a] = make_float4(x, x, y, y);
        atoms_zw[a] = make_float4(z, z, sq, sq);
    }
    __syncthreads();

    const int wave = tid >> 6;
    const int lane = tid & 63;

    const f32x2 NEG2 = {-2.0f, -2.0f};

    const int iA = rowbase + wave * 2;            // ONE row pair per wave
    const int iB = iA + 1;
    const float4 axy = atoms_xy[iA];              // uniform -> broadcast read
    const float4 azw = atoms_zw[iA];
    const float4 bxy = atoms_xy[iB];
    const float4 bzw = atoms_zw[iB];
    const f32x2 CX = {axy.x, bxy.x};
    const f32x2 CY = {axy.z, bxy.z};
    const f32x2 CZ = {azw.x, bzw.x};
    const f32x2 CW = {azw.z, bzw.z};
    const float4 cA = make_float4(axy.x, axy.z, azw.x, azw.z);  // epilogue
    const float4 cB = make_float4(bxy.x, bxy.z, bzw.x, bzw.z);

    // ---- build 8 UNIQUE keys per lane, rows A,B packed in pk-f32;
    //      LDS pairs feed pk ops directly (no broadcast movs) ----
    unsigned qA[8], qB[8];
#pragma unroll
    for (int c = 0; c < 8; ++c) {
        const int j = c * 64 + lane;
        const float4 p0 = atoms_xy[j];            // {x,x,y,y} conflict-free
        const float4 p1 = atoms_zw[j];            // {z,z,q,q} conflict-free
        const f32x2 px = {p0.x, p0.y};
        const f32x2 py = {p0.z, p0.w};
        const f32x2 pz = {p1.x, p1.y};
        const f32x2 pw = {p1.z, p1.w};
        // np einsum order: ((xi*xj + yi*yj) + zi*zj), exact per half
        const f32x2 txx = pk_mul(CX, px);
        const f32x2 tyy = pk_mul(CY, py);
        const f32x2 sxy = pk_add(txx, tyy);
        const f32x2 tzz = pk_mul(CZ, pz);
        const f32x2 dot = pk_add(sxy, tzz);
        // d2 = (ci.w + pj.w) - 2*dot == (ci.w + pj.w) + (-2)*dot exactly
        const f32x2 sw  = pk_add(CW, pw);
        const f32x2 m2  = pk_mul(dot, NEG2);
        const f32x2 d2p = pk_add(sw, m2);
        const float d2A = fmaxf(d2p.x, 0.0f);
        const float d2B = fmaxf(d2p.y, 0.0f);
        qA[c] = ((j != iA) && (d2A <= 100.0f))
                    ? ((__float_as_uint(d2A) & 0xFFFFFE00u) | (unsigned)j)
                    : (0x7F800000u | (unsigned)j);
        qB[c] = ((j != iB) && (d2B <= 100.0f))
                    ? ((__float_as_uint(d2B) & 0xFFFFFE00u) | (unsigned)j)
                    : (0x7F800000u | (unsigned)j);
    }

    // ---- exponent binary search: 3 rounds over L[i]=(0x7E+i)<<23 ----
    // (d2 thresholds 0.5,1,2,4,8,16,32). Largest i with count(<L[i])<32.
    int loA = -1, hiiA = 7, loB = -1, hiiB = 7;
#pragma unroll
    for (int r = 0; r < 3; ++r) {
        const int mA = (loA + hiiA) >> 1;
        const int mB = (loB + hiiB) >> 1;
        const unsigned CA = (unsigned)((0x7E + mA) << 23);
        const unsigned CB = (unsigned)((0x7E + mB) << 23);
        unsigned ca = 0, cb = 0;
#pragma unroll
        for (int c = 0; c < 8; ++c) {
            ca += (unsigned)__popcll(__ballot(qA[c] < CA));
            cb += (unsigned)__popcll(__ballot(qB[c] < CB));
        }
        if (ca < 32u) loA = mA; else hiiA = mA;
        if (cb < 32u) loB = mB; else hiiB = mB;
    }

    // ---- window bound: common path hi = L[lo+1] (tested-rejected =>
    //      count >= 32). lo outside [0,5]: exact full-walk fallback.
    const bool okA = (loA >= 0) && (loA < 6);
    const bool okB = (loB >= 0) && (loB < 6);
    unsigned hiA, hiB;
    if (okA) {
        hiA = (unsigned)((0x7F + loA) << 23);     // L[loA+1]
    } else {
        unsigned X = full_walk(qA);
        hiA = X + (1u << 21);
        if (count_lt(qA, hiA) > 64u) {            // pathological refine
            for (int bit = 20; bit >= 0; --bit) {
                const unsigned C = X | (1u << bit);
                if (count_lt(qA, C) < 32u) X = C;
            }
            hiA = X + 1u;
        }
    }
    if (okB) {
        hiB = (unsigned)((0x7F + loB) << 23);
    } else {
        unsigned X = full_walk(qB);
        hiB = X + (1u << 21);
        if (count_lt(qB, hiB) > 64u) {
            for (int bit = 20; bit >= 0; --bit) {
                const unsigned C = X | (1u << bit);
                if (count_lt(qB, C) < 32u) X = C;
            }
            hiB = X + 1u;
        }
    }

    // ---- compact (ballots -> SGPR masks, prefix, scatter); t == W ----
    unsigned long long mskA[8], mskB[8];
#pragma unroll
    for (int c = 0; c < 8; ++c) {
        mskA[c] = __ballot(qA[c] < hiA);
        mskB[c] = __ballot(qB[c] < hiB);
    }
    unsigned tA = 0, tB = 0, offA[8], offB[8];
#pragma unroll
    for (int c = 0; c < 8; ++c) {
        offA[c] = tA; tA += (unsigned)__popcll(mskA[c]);
        offB[c] = tB; tB += (unsigned)__popcll(mskB[c]);
    }
    wbuf[wave][0][lane] = 0xFFFFFFFFu;
    wbuf[wave][1][lane] = 0xFFFFFFFFu;
#pragma unroll
    for (int c = 0; c < 8; ++c) {
        if (qA[c] < hiA) wbuf[wave][0][offA[c] + mbcnt64(mskA[c])] = qA[c];
        if (qB[c] < hiB) wbuf[wave][1][offB[c] + mbcnt64(mskB[c])] = qB[c];
    }

    // ---- repair (W>64 on common path): exact mantissa+refine, redo ----
    if (okA && tA > 64u) {
        unsigned X = (unsigned)((0x7E + loA) << 23);   // L[loA], count<32
        for (int bit = 22; bit >= 21; --bit) {
            const unsigned C = X | (1u << bit);
            if (count_lt(qA, C) < 32u) X = C;
        }
        hiA = X + (1u << 21);
        if (count_lt(qA, hiA) > 64u) {
            for (int bit = 20; bit >= 0; --bit) {
                const unsigned C = X | (1u << bit);
                if (count_lt(qA, C) < 32u) X = C;
            }
            hiA = X + 1u;
        }
        wbuf[wave][0][lane] = 0xFFFFFFFFu;
        unsigned t = 0;
#pragma unroll
        for (int c = 0; c < 8; ++c) {
            const bool s = (qA[c] < hiA);
            const unsigned long long m = __ballot(s);
            if (s) wbuf[wave][0][t + mbcnt64(m)] = qA[c];
            t += (unsigned)__popcll(m);
        }
    }
    if (okB && tB > 64u) {
        unsigned X = (unsigned)((0x7E + loB) << 23);
        for (int bit = 22; bit >= 21; --bit) {
            const unsigned C = X | (1u << bit);
            if (count_lt(qB, C) < 32u) X = C;
        }
        hiB = X + (1u << 21);
        if (count_lt(qB, hiB) > 64u) {
            for (int bit = 20; bit >= 0; --bit) {
                const unsigned C = X | (1u << bit);
                if (count_lt(qB, C) < 32u) X = C;
            }
            hiB = X + 1u;
        }
        wbuf[wave][1][lane] = 0xFFFFFFFFu;
        unsigned t = 0;
#pragma unroll
        for (int c = 0; c < 8; ++c) {
            const bool s = (qB[c] < hiB);
            const unsigned long long m = __ballot(s);
            if (s) wbuf[wave][1][t + mbcnt64(m)] = qB[c];
            t += (unsigned)__popcll(m);
        }
    }

    unsigned vA = wbuf[wave][0][lane];   // per-wave LDS is in-order
    unsigned vB = wbuf[wave][1][lane];

    // ---- sort: heads + half-cleaners per row, then ONE shared tail ----
    bitonic_head2(vA, vB, lane);         // K=2..32, both rows
    bstep2<64, 32>(vA, vB, lane);        // half-cleaner: 32 smallest low
    // pack: A-low stays lanes 0-31; B-low -> lanes 32-63
    unsigned z = (lane & 32) ? xpart<32>(vB, lane) : vA;
    // final ascending merge of each bitonic 32-half; strides never cross
    // the 32-boundary and keepmin=(lane&J)==0 is correct for both halves
    bstep<64, 16>(z, lane); bstep<64, 8>(z, lane); bstep<64, 4>(z, lane);
    bstep<64, 2>(z, lane);  bstep<64, 1>(z, lane);

    // ---- epilogue: row A on lanes 0..31, row B on lanes 32..63; each
    //      of the 3 stores is a contiguous 256 B wave store.
    const int half = lane >> 5;
    const int l32  = lane & 31;
    const unsigned vv = z;
    const int gi   = iA + half;               // center atom (local idx)
    const int gdst = base + gi;
    const float4 ci = half ? cB : cA;
    float w = 0.0f;
    float srcf = (float)gdst;                 // sentinel -> self-edge, w=0
    if (vv < 0x7F800000u) {
        const int j = (int)(vv & 511u);
        const float4 p0 = atoms_xy[j];        // {x,x,y,y}
        const float4 p1 = atoms_zw[j];        // {z,z,q,q}
        const float pjx = p0.x, pjy = p0.z, pjz = p1.x, pjw = p1.z;
        float dot = __fadd_rn(__fadd_rn(__fmul_rn(ci.x, pjx),
                                        __fmul_rn(ci.y, pjy)),
                              __fmul_rn(ci.z, pjz));
        float d2 = __fsub_rn(__fadd_rn(ci.w, pjw),
                             __fmul_rn(2.0f, dot));
        d2 = fmaxf(d2, 0.0f);
        w = __fsqrt_rn(fmaxf(d2, 1e-12f));
        srcf = (float)(base + j);
    }
    const size_t eb = (size_t)gdst * 32 + (size_t)l32;
    out[eb]                     = srcf;          // src
    out[(size_t)EDGES + eb]     = (float)gdst;   // dst
    out[(size_t)EDGES * 2 + eb] = w;             // weight
}

extern "C" void kernel_launch(void* const* d_in, const int* in_sizes, int n_in,
                              void* d_out, int out_size, void* d_ws, size_t ws_size,
                              hipStream_t stream) {
    (void)in_sizes; (void)n_in; (void)d_ws; (void)ws_size; (void)out_size;
    const float* pos = (const float*)d_in[0];   // [N,3] f32
    float* out       = (float*)d_out;           // [3E] f32

    RadiusInteractionGraph_73246372266582_kernel<<<dim3(8192), dim3(256), 0,
                                                   stream>>>(pos, out);
}

// Round 9
// 96.491 us; speedup vs baseline: 1.0696x; 1.0124x over previous
//

#include <hip/hip_runtime.h>

// RadiusInteractionGraph: B=128 molecules x 512 atoms, K=32 NN, cutoff 10.
// d_out is FLOAT32: [E] src ++ [E] dst ++ [E] weight, E = 128*512*32.
//
// R30 = R29 (one row-pair/wave, 8192 blocks, exponent binary search +
// direct-window compact + shared sort tail, PASS @45.4us) CONSOLIDATED:
// R29's pre-duplicated LDS removed the pk-build broadcast movs but cost
// 2x build LDS bytes, 2x epilogue gathers, conflicts 178K->1.07M, LDS
// 10->18KB. R30 keeps the mov-free build via VOP3P op_sel BROADCASTS
// instead: v_pk_*_f32 with op_sel:[0,0] op_sel_hi:[1,0] computes
// d.lo=a.lo OP b.lo, d.hi=a.hi OP b.lo (b.lo broadcast inside the
// instruction; op_sel:[0,1] op_sel_hi:[1,1] broadcasts b.hi). So the
// classic atoms[512]={x,y,z,|p|^2} layout returns: ONE ds_read_b128 per
// chunk (8KB/wave build traffic), ONE epilogue gather, 10KB LDS block.
// Per-half arithmetic is the same IEEE RN mul/add -> bit-identical.
// Selection semantics bit-identical to lax.top_k stable order via
// key=(d2_hi23|j); exact __f*_rn np arithmetic (s-2*dot == s+(-2)*dot
// under RN); sentinel 0x7F800000|j -> pad self-edge; repair/fallback
// paths exact (R19/R26/R27 lineage).

constexpr int EDGES = 128 * 512 * 32;   // 2097152

typedef float f32x2 __attribute__((ext_vector_type(2)));

// plain packed ops (both halves independent)
static __device__ __forceinline__ f32x2 pk_mul(f32x2 a, f32x2 b) {
    f32x2 d;
    asm("v_pk_mul_f32 %0, %1, %2" : "=v"(d) : "v"(a), "v"(b));
    return d;
}
static __device__ __forceinline__ f32x2 pk_add(f32x2 a, f32x2 b) {
    f32x2 d;
    asm("v_pk_add_f32 %0, %1, %2" : "=v"(d) : "v"(a), "v"(b));
    return d;
}
// broadcast b.lo into both halves: d.lo=a.lo*b.lo, d.hi=a.hi*b.lo
static __device__ __forceinline__ f32x2 pk_mul_blo(f32x2 a, f32x2 b) {
    f32x2 d;
    asm("v_pk_mul_f32 %0, %1, %2 op_sel:[0,0] op_sel_hi:[1,0]"
        : "=v"(d) : "v"(a), "v"(b));
    return d;
}
// broadcast b.hi into both halves: d.lo=a.lo*b.hi, d.hi=a.hi*b.hi
static __device__ __forceinline__ f32x2 pk_mul_bhi(f32x2 a, f32x2 b) {
    f32x2 d;
    asm("v_pk_mul_f32 %0, %1, %2 op_sel:[0,1] op_sel_hi:[1,1]"
        : "=v"(d) : "v"(a), "v"(b));
    return d;
}
// broadcast b.hi into both halves (add)
static __device__ __forceinline__ f32x2 pk_add_bhi(f32x2 a, f32x2 b) {
    f32x2 d;
    asm("v_pk_add_f32 %0, %1, %2 op_sel:[0,1] op_sel_hi:[1,1]"
        : "=v"(d) : "v"(a), "v"(b));
    return d;
}

static __device__ __forceinline__ unsigned umin2(unsigned a, unsigned b) {
    return a < b ? a : b;
}
static __device__ __forceinline__ unsigned umax2(unsigned a, unsigned b) {
    return a > b ? a : b;
}

static __device__ __forceinline__ unsigned mbcnt64(unsigned long long m) {
    return __builtin_amdgcn_mbcnt_hi(
        (unsigned)(m >> 32),
        __builtin_amdgcn_mbcnt_lo((unsigned)m, 0u));
}

static __device__ __forceinline__ unsigned count_lt(const unsigned q[8],
                                                    unsigned C) {
    unsigned cnt = 0;
#pragma unroll
    for (int c = 0; c < 8; ++c)
        cnt += (unsigned)__popcll(__ballot(q[c] < C));
    return cnt;
}

// original greedy MSB walk over bits 30..21 (exact; rare fallback path)
static __device__ __forceinline__ unsigned full_walk(const unsigned q[8]) {
    unsigned X = 0u;
    for (int bit = 30; bit >= 21; --bit) {
        const unsigned C = X | (1u << bit);
        if (count_lt(q, C) < 32u) X = C;
    }
    return X;
}

// xor-partner fetch, all-VALU (no LDS pipe). Patterns verified (R24 PASS):
//  quad_perm 0xB1 = ^1, 0x4E = ^2, 0x1B = ^3; 0x141 row_half_mirror = ^7
//  within 8; 0x128 row_ror:8 = ^8 within 16 (+8 mod 16 == ^8).
template <int J>
static __device__ __forceinline__ unsigned xpart(unsigned v, int lane) {
    if constexpr (J == 1) {
        return (unsigned)__builtin_amdgcn_update_dpp(
            (int)v, (int)v, 0xB1, 0xF, 0xF, false);
    } else if constexpr (J == 2) {
        return (unsigned)__builtin_amdgcn_update_dpp(
            (int)v, (int)v, 0x4E, 0xF, 0xF, false);
    } else if constexpr (J == 4) {
        const int t = __builtin_amdgcn_update_dpp(
            (int)v, (int)v, 0x141, 0xF, 0xF, false);   // ^7 within 8
        return (unsigned)__builtin_amdgcn_update_dpp(
            t, t, 0x1B, 0xF, 0xF, false);              // ^3 -> net ^4
    } else if constexpr (J == 8) {
        return (unsigned)__builtin_amdgcn_update_dpp(
            (int)v, (int)v, 0x128, 0xF, 0xF, false);   // row_ror:8 = ^8
    } else if constexpr (J == 16) {
#if __has_builtin(__builtin_amdgcn_permlane16_swap)
        auto r = __builtin_amdgcn_permlane16_swap((int)v, (int)v, false, false);
        return (unsigned)((lane & 16) ? r[0] : r[1]);
#else
        return (unsigned)__shfl_xor((int)v, 16, 64);
#endif
    } else {
#if __has_builtin(__builtin_amdgcn_permlane32_swap)
        auto r = __builtin_amdgcn_permlane32_swap((int)v, (int)v, false, false);
        return (unsigned)((lane & 32) ? r[0] : r[1]);
#else
        return (unsigned)__shfl_xor((int)v, 32, 64);
#endif
    }
}

template <int K, int J>
static __device__ __forceinline__ void bstep(unsigned& v, int lane) {
    const unsigned p = xpart<J>(v, lane);
    const bool keepmin = (((lane & J) == 0) == ((lane & K) == 0));
    const unsigned mn = umin2(v, p);
    const unsigned mx = umax2(v, p);
    v = keepmin ? mn : mx;
}

// one step applied to both rows (independent chains fill stall slots;
// keepmin computed once)
template <int K, int J>
static __device__ __forceinline__ void bstep2(unsigned& a, unsigned& b,
                                              int lane) {
    const unsigned pa = xpart<J>(a, lane);
    const unsigned pb = xpart<J>(b, lane);
    const bool keepmin = (((lane & J) == 0) == ((lane & K) == 0));
    a = keepmin ? umin2(a, pa) : umax2(a, pa);
    b = keepmin ? umin2(b, pb) : umax2(b, pb);
}

// bitonic stages K=2..32 (15 steps/row), rows interleaved
static __device__ __forceinline__ void bitonic_head2(unsigned& a, unsigned& b,
                                                     int lane) {
    bstep2<2, 1>(a, b, lane);
    bstep2<4, 2>(a, b, lane);   bstep2<4, 1>(a, b, lane);
    bstep2<8, 4>(a, b, lane);   bstep2<8, 2>(a, b, lane);
    bstep2<8, 1>(a, b, lane);
    bstep2<16, 8>(a, b, lane);  bstep2<16, 4>(a, b, lane);
    bstep2<16, 2>(a, b, lane);  bstep2<16, 1>(a, b, lane);
    bstep2<32, 16>(a, b, lane); bstep2<32, 8>(a, b, lane);
    bstep2<32, 4>(a, b, lane);  bstep2<32, 2>(a, b, lane);
    bstep2<32, 1>(a, b, lane);
}

__global__ __launch_bounds__(256)
void RadiusInteractionGraph_73246372266582_kernel(const float* __restrict__ pos,
                                                  float* __restrict__ out) {
    __shared__ float4 atoms[512];        // x, y, z, |p|^2
    __shared__ unsigned wbuf[4][2][64];  // per-wave, per-row window buffer

    const int tid     = threadIdx.x;
    const int b       = blockIdx.x >> 6;          // 64 blocks per molecule
    const int rowbase = (blockIdx.x & 63) * 8;    // 8 rows per block
    const int base    = b * 512;

    for (int a = tid; a < 512; a += 256) {
        float x = pos[(base + a) * 3 + 0];
        float y = pos[(base + a) * 3 + 1];
        float z = pos[(base + a) * 3 + 2];
        // np: sum(p*p) = (x*x + y*y) + z*z, sequential f32, no fma
        float sq = __fadd_rn(__fadd_rn(__fmul_rn(x, x), __fmul_rn(y, y)),
                             __fmul_rn(z, z));
        atoms[a] = make_float4(x, y, z, sq);
    }
    __syncthreads();

    const int wave = tid >> 6;
    const int lane = tid & 63;

    const f32x2 NEG2 = {-2.0f, -2.0f};

    const int iA = rowbase + wave * 2;            // ONE row pair per wave
    const int iB = iA + 1;
    const float4 cA = atoms[iA];                  // uniform -> broadcast read
    const float4 cB = atoms[iB];
    const f32x2 CX = {cA.x, cB.x};
    const f32x2 CY = {cA.y, cB.y};
    const f32x2 CZ = {cA.z, cB.z};
    const f32x2 CW = {cA.w, cB.w};

    // ---- build 8 UNIQUE keys per lane, rows A,B packed in pk-f32;
    //      op_sel broadcasts pull pj components straight from the b128
    //      quad (no broadcast movs, single LDS read per chunk) ----
    unsigned qA[8], qB[8];
#pragma unroll
    for (int c = 0; c < 8; ++c) {
        const int j = c * 64 + lane;
        const float4 pj = atoms[j];               // one ds_read_b128
        const f32x2 pxy = {pj.x, pj.y};           // low halves of the quad
        const f32x2 pzw = {pj.z, pj.w};
        // np einsum order: ((xi*xj + yi*yj) + zi*zj), exact per half
        const f32x2 txx = pk_mul_blo(CX, pxy);    // {cA.x*xj, cB.x*xj}
        const f32x2 tyy = pk_mul_bhi(CY, pxy);    // {cA.y*yj, cB.y*yj}
        const f32x2 sxy = pk_add(txx, tyy);
        const f32x2 tzz = pk_mul_blo(CZ, pzw);    // {cA.z*zj, cB.z*zj}
        const f32x2 dot = pk_add(sxy, tzz);
        // d2 = (ci.w + pj.w) - 2*dot == (ci.w + pj.w) + (-2)*dot exactly
        const f32x2 sw  = pk_add_bhi(CW, pzw);    // {cA.w+qj, cB.w+qj}
        const f32x2 m2  = pk_mul(dot, NEG2);
        const f32x2 d2p = pk_add(sw, m2);
        const float d2A = fmaxf(d2p.x, 0.0f);
        const float d2B = fmaxf(d2p.y, 0.0f);
        qA[c] = ((j != iA) && (d2A <= 100.0f))
                    ? ((__float_as_uint(d2A) & 0xFFFFFE00u) | (unsigned)j)
                    : (0x7F800000u | (unsigned)j);
        qB[c] = ((j != iB) && (d2B <= 100.0f))
                    ? ((__float_as_uint(d2B) & 0xFFFFFE00u) | (unsigned)j)
                    : (0x7F800000u | (unsigned)j);
    }

    // ---- exponent binary search: 3 rounds over L[i]=(0x7E+i)<<23 ----
    // (d2 thresholds 0.5,1,2,4,8,16,32). Largest i with count(<L[i])<32.
    int loA = -1, hiiA = 7, loB = -1, hiiB = 7;
#pragma unroll
    for (int r = 0; r < 3; ++r) {
        const int mA = (loA + hiiA) >> 1;
        const int mB = (loB + hiiB) >> 1;
        const unsigned CA = (unsigned)((0x7E + mA) << 23);
        const unsigned CB = (unsigned)((0x7E + mB) << 23);
        unsigned ca = 0, cb = 0;
#pragma unroll
        for (int c = 0; c < 8; ++c) {
            ca += (unsigned)__popcll(__ballot(qA[c] < CA));
            cb += (unsigned)__popcll(__ballot(qB[c] < CB));
        }
        if (ca < 32u) loA = mA; else hiiA = mA;
        if (cb < 32u) loB = mB; else hiiB = mB;
    }

    // ---- window bound: common path hi = L[lo+1] (tested-rejected =>
    //      count >= 32). lo outside [0,5]: exact full-walk fallback.
    const bool okA = (loA >= 0) && (loA < 6);
    const bool okB = (loB >= 0) && (loB < 6);
    unsigned hiA, hiB;
    if (okA) {
        hiA = (unsigned)((0x7F + loA) << 23);     // L[loA+1]
    } else {
        unsigned X = full_walk(qA);
        hiA = X + (1u << 21);
        if (count_lt(qA, hiA) > 64u) {            // pathological refine
            for (int bit = 20; bit >= 0; --bit) {
                const unsigned C = X | (1u << bit);
                if (count_lt(qA, C) < 32u) X = C;
            }
            hiA = X + 1u;
        }
    }
    if (okB) {
        hiB = (unsigned)((0x7F + loB) << 23);
    } else {
        unsigned X = full_walk(qB);
        hiB = X + (1u << 21);
        if (count_lt(qB, hiB) > 64u) {
            for (int bit = 20; bit >= 0; --bit) {
                const unsigned C = X | (1u << bit);
                if (count_lt(qB, C) < 32u) X = C;
            }
            hiB = X + 1u;
        }
    }

    // ---- compact (ballots -> SGPR masks, prefix, scatter); t == W ----
    unsigned long long mskA[8], mskB[8];
#pragma unroll
    for (int c = 0; c < 8; ++c) {
        mskA[c] = __ballot(qA[c] < hiA);
        mskB[c] = __ballot(qB[c] < hiB);
    }
    unsigned tA = 0, tB = 0, offA[8], offB[8];
#pragma unroll
    for (int c = 0; c < 8; ++c) {
        offA[c] = tA; tA += (unsigned)__popcll(mskA[c]);
        offB[c] = tB; tB += (unsigned)__popcll(mskB[c]);
    }
    wbuf[wave][0][lane] = 0xFFFFFFFFu;
    wbuf[wave][1][lane] = 0xFFFFFFFFu;
#pragma unroll
    for (int c = 0; c < 8; ++c) {
        if (qA[c] < hiA) wbuf[wave][0][offA[c] + mbcnt64(mskA[c])] = qA[c];
        if (qB[c] < hiB) wbuf[wave][1][offB[c] + mbcnt64(mskB[c])] = qB[c];
    }

    // ---- repair (W>64 on common path): exact mantissa+refine, redo ----
    if (okA && tA > 64u) {
        unsigned X = (unsigned)((0x7E + loA) << 23);   // L[loA], count<32
        for (int bit = 22; bit >= 21; --bit) {
            const unsigned C = X | (1u << bit);
            if (count_lt(qA, C) < 32u) X = C;
        }
        hiA = X + (1u << 21);
        if (count_lt(qA, hiA) > 64u) {
            for (int bit = 20; bit >= 0; --bit) {
                const unsigned C = X | (1u << bit);
                if (count_lt(qA, C) < 32u) X = C;
            }
            hiA = X + 1u;
        }
        wbuf[wave][0][lane] = 0xFFFFFFFFu;
        unsigned t = 0;
#pragma unroll
        for (int c = 0; c < 8; ++c) {
            const bool s = (qA[c] < hiA);
            const unsigned long long m = __ballot(s);
            if (s) wbuf[wave][0][t + mbcnt64(m)] = qA[c];
            t += (unsigned)__popcll(m);
        }
    }
    if (okB && tB > 64u) {
        unsigned X = (unsigned)((0x7E + loB) << 23);
        for (int bit = 22; bit >= 21; --bit) {
            const unsigned C = X | (1u << bit);
            if (count_lt(qB, C) < 32u) X = C;
        }
        hiB = X + (1u << 21);
        if (count_lt(qB, hiB) > 64u) {
            for (int bit = 20; bit >= 0; --bit) {
                const unsigned C = X | (1u << bit);
                if (count_lt(qB, C) < 32u) X = C;
            }
            hiB = X + 1u;
        }
        wbuf[wave][1][lane] = 0xFFFFFFFFu;
        unsigned t = 0;
#pragma unroll
        for (int c = 0; c < 8; ++c) {
            const bool s = (qB[c] < hiB);
            const unsigned long long m = __ballot(s);
            if (s) wbuf[wave][1][t + mbcnt64(m)] = qB[c];
            t += (unsigned)__popcll(m);
        }
    }

    unsigned vA = wbuf[wave][0][lane];   // per-wave LDS is in-order
    unsigned vB = wbuf[wave][1][lane];

    // ---- sort: heads + half-cleaners per row, then ONE shared tail ----
    bitonic_head2(vA, vB, lane);         // K=2..32, both rows
    bstep2<64, 32>(vA, vB, lane);        // half-cleaner: 32 smallest low
    // pack: A-low stays lanes 0-31; B-low -> lanes 32-63
    unsigned z = (lane & 32) ? xpart<32>(vB, lane) : vA;
    // final ascending merge of each bitonic 32-half; strides never cross
    // the 32-boundary and keepmin=(lane&J)==0 is correct for both halves
    bstep<64, 16>(z, lane); bstep<64, 8>(z, lane); bstep<64, 4>(z, lane);
    bstep<64, 2>(z, lane);  bstep<64, 1>(z, lane);

    // ---- epilogue: row A on lanes 0..31, row B on lanes 32..63; each
    //      of the 3 stores is a contiguous 256 B wave store.
    const int half = lane >> 5;
    const int l32  = lane & 31;
    const unsigned vv = z;
    const int gi   = iA + half;               // center atom (local idx)
    const int gdst = base + gi;
    const float4 ci = half ? cB : cA;
    float w = 0.0f;
    float srcf = (float)gdst;                 // sentinel -> self-edge, w=0
    if (vv < 0x7F800000u) {
        const int j = (int)(vv & 511u);
        const float4 pj = atoms[j];           // single random gather
        float dot = __fadd_rn(__fadd_rn(__fmul_rn(ci.x, pj.x),
                                        __fmul_rn(ci.y, pj.y)),
                              __fmul_rn(ci.z, pj.z));
        float d2 = __fsub_rn(__fadd_rn(ci.w, pj.w),
                             __fmul_rn(2.0f, dot));
        d2 = fmaxf(d2, 0.0f);
        w = __fsqrt_rn(fmaxf(d2, 1e-12f));
        srcf = (float)(base + j);
    }
    const size_t eb = (size_t)gdst * 32 + (size_t)l32;
    out[eb]                     = srcf;          // src
    out[(size_t)EDGES + eb]     = (float)gdst;   // dst
    out[(size_t)EDGES * 2 + eb] = w;             // weight
}

extern "C" void kernel_launch(void* const* d_in, const int* in_sizes, int n_in,
                              void* d_out, int out_size, void* d_ws, size_t ws_size,
                              hipStream_t stream) {
    (void)in_sizes; (void)n_in; (void)d_ws; (void)ws_size; (void)out_size;
    const float* pos = (const float*)d_in[0];   // [N,3] f32
    float* out       = (float*)d_out;           // [3E] f32

    RadiusInteractionGraph_73246372266582_kernel<<<dim3(8192), dim3(256), 0,
                                                   stream>>>(pos, out);
}